// Round 1
// baseline (243.496 us; speedup 1.0000x reference)
//
#include <hip/hip_runtime.h>
#include <hip/hip_bf16.h>
#include <math.h>

#define NV 6890   // SMPL vertex count
#define NC 1024   // contact vertices

// ---------------------------------------------------------------------------
// Detect how the bool geomask was transferred:
//   mode 0: 4-byte elements (int32 0/1, or f32 0.0/1.0 -> word 0x3F800000)
//   mode 1: 1-byte elements (numpy bool)
// For 4-byte storage every word is in {0,1,0x3F800000}; for random packed
// bool bytes the probability all 64 words land in that set is ~0.
// ---------------------------------------------------------------------------
__global__ void detect_mode_kernel(const unsigned int* __restrict__ gm,
                                   int* __restrict__ flag) {
    if (threadIdx.x == 0 && blockIdx.x == 0) {
        int byteMode = 0;
        for (int k = 0; k < 64; ++k) {
            unsigned int w = gm[k];
            if (!(w == 0u || w == 1u || w == 0x3F800000u)) { byteMode = 1; break; }
        }
        flag[0] = byteMode;
    }
}

// ---------------------------------------------------------------------------
// One block per contact row i (1024 blocks x 256 threads).
// All 1024 contact coords staged in LDS (12 KB). Each thread scans 4 columns,
// lexicographic (score, idx) min gives exactly jnp.argmin's first-tie /
// all-inf->0 semantics. Distance recomputed at the winner (handles the
// all-masked row: argmin=0 -> v2v_min = d(i,0), matching the reference).
// ---------------------------------------------------------------------------
__global__ __launch_bounds__(256) void contact_row_kernel(
        const int* __restrict__ pc, const float* __restrict__ verts,
        const void* __restrict__ gm, const int* __restrict__ flag,
        float* __restrict__ tvals, float* __restrict__ atom_out, int atomicMode) {
    __shared__ float sx[NC], sy[NC], sz[NC];
    __shared__ int   spc[NC];
    __shared__ float wbest[4];
    __shared__ int   widx[4];

    const int tid = threadIdx.x;
    for (int j = tid; j < NC; j += 256) {
        int v = pc[j];
        spc[j] = v;
        sx[j] = verts[3 * v + 0];
        sy[j] = verts[3 * v + 1];
        sz[j] = verts[3 * v + 2];
    }
    __syncthreads();

    const int   i  = blockIdx.x;
    const float xi = sx[i], yi = sy[i], zi = sz[i];
    const int   vi = spc[i];
    const int   byteMode = flag[0];
    const unsigned char* gmb = (const unsigned char*)gm + (size_t)vi * NV;
    const unsigned int*  gmi = (const unsigned int*)gm  + (size_t)vi * NV;

    float best = INFINITY;
    int   bidx = 0x7FFFFFFF;
    for (int j = tid; j < NC; j += 256) {
        float dx = xi - sx[j], dy = yi - sy[j], dz = zi - sz[j];
        float d2 = dx * dx + dy * dy + dz * dz;
        int vj = spc[j];
        unsigned int m = byteMode ? (unsigned int)gmb[vj] : gmi[vj];
        float s = m ? d2 : INFINITY;
        if (s < best || (s == best && j < bidx)) { best = s; bidx = j; }
    }

    // wave (64-lane) butterfly-free down-shuffle argmin reduction
    #pragma unroll
    for (int off = 32; off > 0; off >>= 1) {
        float ob = __shfl_down(best, off, 64);
        int   oi = __shfl_down(bidx, off, 64);
        if (ob < best || (ob == best && oi < bidx)) { best = ob; bidx = oi; }
    }
    if ((tid & 63) == 0) { wbest[tid >> 6] = best; widx[tid >> 6] = bidx; }
    __syncthreads();

    if (tid == 0) {
        best = wbest[0]; bidx = widx[0];
        #pragma unroll
        for (int w = 1; w < 4; ++w) {
            if (wbest[w] < best || (wbest[w] == best && widx[w] < bidx)) {
                best = wbest[w]; bidx = widx[w];
            }
        }
        float dx = xi - sx[bidx], dy = yi - sy[bidx], dz = zi - sz[bidx];
        float d  = sqrtf(dx * dx + dy * dy + dz * dz);
        float t  = tanhf(d);
        if (atomicMode) {
            atomicAdd(atom_out, t * (1.0f / (float)NC));
        } else {
            tvals[i] = t;
        }
    }
}

// ---------------------------------------------------------------------------
// Deterministic mean of the 1024 per-row tanh values.
// ---------------------------------------------------------------------------
__global__ __launch_bounds__(256) void reduce_mean_kernel(
        const float* __restrict__ vals, float* __restrict__ out) {
    __shared__ float wsum[4];
    const int t = threadIdx.x;
    float s = vals[t] + vals[t + 256] + vals[t + 512] + vals[t + 768];
    #pragma unroll
    for (int off = 32; off > 0; off >>= 1) s += __shfl_down(s, off, 64);
    if ((t & 63) == 0) wsum[t >> 6] = s;
    __syncthreads();
    if (t == 0) out[0] = (wsum[0] + wsum[1] + wsum[2] + wsum[3]) * (1.0f / (float)NC);
}

extern "C" void kernel_launch(void* const* d_in, const int* in_sizes, int n_in,
                              void* d_out, int out_size, void* d_ws, size_t ws_size,
                              hipStream_t stream) {
    const int*   pc    = (const int*)d_in[0];    // presented_contact [1024] int32
    const float* verts = (const float*)d_in[1];  // vertices [1,6890,3] f32
    const void*  gm    = d_in[2];                // geomask [6890,6890] bool (storage detected)
    float*       out   = (float*)d_out;          // scalar f32 loss

    int* flag = (int*)d_ws;                      // 4 B detection flag

    detect_mode_kernel<<<1, 64, 0, stream>>>((const unsigned int*)gm, flag);

    if (ws_size >= 256 + NC * sizeof(float)) {
        float* tvals = (float*)((char*)d_ws + 256);
        contact_row_kernel<<<NC, 256, 0, stream>>>(pc, verts, gm, flag, tvals, nullptr, 0);
        reduce_mean_kernel<<<1, 256, 0, stream>>>(tvals, out);
    } else {
        // fallback: zero the scalar output, accumulate atomically
        hipMemsetAsync(d_out, 0, sizeof(float), stream);
        contact_row_kernel<<<NC, 256, 0, stream>>>(pc, verts, gm, flag, nullptr, out, 1);
    }
}

// Round 2
// 234.977 us; speedup vs baseline: 1.0363x; 1.0363x over previous
//
#include <hip/hip_runtime.h>
#include <hip/hip_bf16.h>
#include <math.h>

#define NV 6890   // SMPL vertex count
#define NC 1024   // contact vertices

// ---------------------------------------------------------------------------
// One block per contact row i (1024 blocks x 256 threads).
//
// - geomask storage mode (int32 words vs raw bytes) detected per-block by
//   wave 0 via ballot over the first 64 words (4-byte storage => every word
//   in {0,1,0x3F800000}; random packed bool bytes essentially never are).
//   One coalesced 256B load, no serial latency chain, no extra kernel.
// - The 1024 contact coords are staged in LDS (16 KB).
// - The full geomask row vi (6890 entries) is read COALESCED from global and
//   stored as bytes in LDS (6.9 KB); the 1024 mask lookups then gather from
//   LDS instead of issuing scattered 4-B global reads. Caches are wiped by
//   the harness's 759 MB poison fill each iteration, so coalescing the cold
//   HBM traffic matters: ~27 MB coalesced vs ~50 MB of scattered lines.
// - Lexicographic (score, idx) min reproduces jnp.argmin first-tie /
//   all-inf->0 semantics exactly; argmin over masked d^2 == argmin over
//   masked (d+1). Distance is recomputed at the winner (handles all-masked
//   rows: idx 0 -> v2v_min = d(i, pc[0]), matching the reference).
// ---------------------------------------------------------------------------
__global__ __launch_bounds__(256) void contact_row_kernel(
        const int* __restrict__ pc, const float* __restrict__ verts,
        const void* __restrict__ gm, float* __restrict__ tvals) {
    __shared__ float sx[NC], sy[NC], sz[NC];
    __shared__ int   spc[NC];
    __shared__ unsigned char rowm[NV];
    __shared__ int   modeSh;
    __shared__ float wbest[4];
    __shared__ int   widx[4];

    const int tid = threadIdx.x;

    // --- storage-mode detection (wave 0 only, one coalesced load) ---
    if (tid < 64) {
        unsigned int w = ((const unsigned int*)gm)[tid];
        bool ok4 = (w == 0u || w == 1u || w == 0x3F800000u);
        unsigned long long b = __ballot(ok4);
        if (tid == 0) modeSh = (b == ~0ULL) ? 0 : 1;  // 0: 4-byte words, 1: bytes
    }

    // --- stage contact vertex coords ---
    for (int j = tid; j < NC; j += 256) {
        int v = pc[j];
        spc[j] = v;
        sx[j] = verts[3 * v + 0];
        sy[j] = verts[3 * v + 1];
        sz[j] = verts[3 * v + 2];
    }
    __syncthreads();

    const int i  = blockIdx.x;
    const int vi = spc[i];
    const int mode = modeSh;

    // --- stage geomask row vi into LDS as bytes, coalesced ---
    if (mode == 0) {
        const unsigned int* row = (const unsigned int*)gm + (size_t)vi * NV;
        for (int k = tid; k < NV; k += 256) rowm[k] = (unsigned char)(row[k] != 0u);
    } else {
        const unsigned char* row = (const unsigned char*)gm + (size_t)vi * NV;
        for (int k = tid; k < NV; k += 256) rowm[k] = row[k];
    }
    __syncthreads();

    const float xi = sx[i], yi = sy[i], zi = sz[i];
    float best = INFINITY;
    int   bidx = 0x7FFFFFFF;
    #pragma unroll
    for (int u = 0; u < NC / 256; ++u) {
        int j = tid + u * 256;
        float dx = xi - sx[j], dy = yi - sy[j], dz = zi - sz[j];
        float d2 = dx * dx + dy * dy + dz * dz;
        float s = rowm[spc[j]] ? d2 : INFINITY;
        if (s < best || (s == best && j < bidx)) { best = s; bidx = j; }
    }

    // --- wave (64-lane) argmin reduction, then cross-wave via LDS ---
    #pragma unroll
    for (int off = 32; off > 0; off >>= 1) {
        float ob = __shfl_down(best, off, 64);
        int   oi = __shfl_down(bidx, off, 64);
        if (ob < best || (ob == best && oi < bidx)) { best = ob; bidx = oi; }
    }
    if ((tid & 63) == 0) { wbest[tid >> 6] = best; widx[tid >> 6] = bidx; }
    __syncthreads();

    if (tid == 0) {
        best = wbest[0]; bidx = widx[0];
        #pragma unroll
        for (int w = 1; w < 4; ++w) {
            if (wbest[w] < best || (wbest[w] == best && widx[w] < bidx)) {
                best = wbest[w]; bidx = widx[w];
            }
        }
        float dx = xi - sx[bidx], dy = yi - sy[bidx], dz = zi - sz[bidx];
        float d  = sqrtf(dx * dx + dy * dy + dz * dz);
        tvals[i] = tanhf(d);
    }
}

// ---------------------------------------------------------------------------
// Deterministic mean of the 1024 per-row tanh values.
// ---------------------------------------------------------------------------
__global__ __launch_bounds__(256) void reduce_mean_kernel(
        const float* __restrict__ vals, float* __restrict__ out) {
    __shared__ float wsum[4];
    const int t = threadIdx.x;
    float s = vals[t] + vals[t + 256] + vals[t + 512] + vals[t + 768];
    #pragma unroll
    for (int off = 32; off > 0; off >>= 1) s += __shfl_down(s, off, 64);
    if ((t & 63) == 0) wsum[t >> 6] = s;
    __syncthreads();
    if (t == 0) out[0] = (wsum[0] + wsum[1] + wsum[2] + wsum[3]) * (1.0f / (float)NC);
}

extern "C" void kernel_launch(void* const* d_in, const int* in_sizes, int n_in,
                              void* d_out, int out_size, void* d_ws, size_t ws_size,
                              hipStream_t stream) {
    const int*   pc    = (const int*)d_in[0];    // presented_contact [1024] int32
    const float* verts = (const float*)d_in[1];  // vertices [1,6890,3] f32
    const void*  gm    = d_in[2];                // geomask [6890,6890] bool (storage detected)
    float*       out   = (float*)d_out;          // scalar f32 loss

    float* tvals = (float*)d_ws;                 // 4 KB of workspace, fully overwritten

    contact_row_kernel<<<NC, 256, 0, stream>>>(pc, verts, gm, tvals);
    reduce_mean_kernel<<<1, 256, 0, stream>>>(tvals, out);
}